// Round 5
// baseline (16.704 us; speedup 1.0000x reference)
//
#include <hip/hip_runtime.h>

// dag[i,j] = s[i,j]*nr[j] * (i<j ? 1 : (i>j ? 1 - s[j,i]*nr[i] : 0))
// s[i,j] = (ep[i,j]+ge[i,j,0]) > ((1-ep[i,j])+ge[i,j,1])
// nr[j]  = 1 - ((rp[j]+gr[j,0]) > ((1-rp[j])+gr[j,1]))

typedef float f4 __attribute__((ext_vector_type(4)));

constexpr int TS = 64;   // 64x64 tiles, 256 threads, 16 elems/thread

__global__ __launch_bounds__(256) void dag_kernel(
    const float*  __restrict__ rp,
    const float2* __restrict__ gr2,
    const float*  __restrict__ ep,
    const f4*     __restrict__ ge4,
    float* __restrict__ out, int n)
{
    __shared__ float Ash[TS][TS + 1];  // raw sample s of tile A; +1 pad
    __shared__ float nrJ[TS];          // nr for cols J..J+63
    __shared__ float nrI[TS];          // nr for cols I..I+63

    // triangular pair decode: (bi,bj), bi <= bj
    int p = blockIdx.x;
    int a = (int)((sqrtf(8.0f * (float)p + 1.0f) - 1.0f) * 0.5f);
    while ((a + 1) * (a + 2) / 2 <= p) ++a;
    while (a * (a + 1) / 2 > p) --a;
    const int bi = p - a * (a + 1) / 2;
    const int bj = a;
    const int I = bi * TS, J = bj * TS;
    const bool diag = (bi == bj);

    const int t  = threadIdx.x;
    const int r0 = t >> 4;          // 0..15
    const int c4 = (t & 15) << 2;   // 0..60

    // ---- issue all streaming loads up front ----
    f4 epA[4], qA0[4], qA1[4];
#pragma unroll
    for (int r = 0; r < 4; ++r) {
        size_t idx = (size_t)(I + r0 + r * 16) * n + (size_t)(J + c4);
        epA[r] = *(const f4*)(ep + idx);
        qA0[r] = ge4[idx >> 1];
        qA1[r] = ge4[(idx >> 1) + 1];
    }
    f4 epB[4], qB0[4], qB1[4];
    if (!diag) {
#pragma unroll
        for (int r = 0; r < 4; ++r) {
            size_t idx = (size_t)(J + r0 + r * 16) * n + (size_t)(I + c4);
            epB[r] = *(const f4*)(ep + idx);
            qB0[r] = ge4[idx >> 1];
            qB1[r] = ge4[(idx >> 1) + 1];
        }
    }

    // ---- root indicators into LDS (sync merges with transpose barrier) ----
    if (t < TS) {
        int j = J + t;
        float pj = rp[j]; float2 g = gr2[j];
        nrJ[t] = ((pj + g.x) > ((1.0f - pj) + g.y)) ? 0.0f : 1.0f;
    } else if (t < 2 * TS) {
        int j = I + (t - TS);
        float pj = rp[j]; float2 g = gr2[j];
        nrI[t - TS] = ((pj + g.x) > ((1.0f - pj) + g.y)) ? 0.0f : 1.0f;
    }

    // ---- tile A samples -> LDS (raw s, nr applied after barrier) ----
    float sA[4][4];
#pragma unroll
    for (int r = 0; r < 4; ++r) {
        int row = r0 + r * 16;
        sA[r][0] = ((epA[r].x + qA0[r].x) > ((1.0f - epA[r].x) + qA0[r].y)) ? 1.0f : 0.0f;
        sA[r][1] = ((epA[r].y + qA0[r].z) > ((1.0f - epA[r].y) + qA0[r].w)) ? 1.0f : 0.0f;
        sA[r][2] = ((epA[r].z + qA1[r].x) > ((1.0f - epA[r].z) + qA1[r].y)) ? 1.0f : 0.0f;
        sA[r][3] = ((epA[r].w + qA1[r].z) > ((1.0f - epA[r].w) + qA1[r].w)) ? 1.0f : 0.0f;
        Ash[row][c4 + 0] = sA[r][0];
        Ash[row][c4 + 1] = sA[r][1];
        Ash[row][c4 + 2] = sA[r][2];
        Ash[row][c4 + 3] = sA[r][3];
    }

    float sB[4][4];
    if (!diag) {
#pragma unroll
        for (int r = 0; r < 4; ++r) {
            sB[r][0] = ((epB[r].x + qB0[r].x) > ((1.0f - epB[r].x) + qB0[r].y)) ? 1.0f : 0.0f;
            sB[r][1] = ((epB[r].y + qB0[r].z) > ((1.0f - epB[r].y) + qB0[r].w)) ? 1.0f : 0.0f;
            sB[r][2] = ((epB[r].z + qB1[r].x) > ((1.0f - epB[r].z) + qB1[r].y)) ? 1.0f : 0.0f;
            sB[r][3] = ((epB[r].w + qB1[r].z) > ((1.0f - epB[r].w) + qB1[r].w)) ? 1.0f : 0.0f;
        }
    }

    __syncthreads();   // single barrier: covers Ash and nrJ/nrI

    if (diag) {
#pragma unroll
        for (int r = 0; r < 4; ++r) {
            int row = r0 + r * 16;
            size_t idx = (size_t)(I + row) * n + (size_t)(J + c4);
            float nr_row = nrJ[row];
            f4 v;
#pragma unroll
            for (int c = 0; c < 4; ++c) {
                int col = c4 + c;
                float x;
                if (row == col)      x = 0.0f;
                else if (row < col)  x = sA[r][c] * nrJ[col];
                else                 x = sA[r][c] * nrJ[col] *
                                         (1.0f - Ash[col][row] * nr_row);
                v[c] = x;
            }
            *(f4*)(out + idx) = v;
        }
    } else {
#pragma unroll
        for (int r = 0; r < 4; ++r) {
            int row = r0 + r * 16;
            size_t idxA = (size_t)(I + row) * n + (size_t)(J + c4);
            // upper tile: i = I+row < j = J+col always
            f4 u;
            u.x = sA[r][0] * nrJ[c4 + 0];
            u.y = sA[r][1] * nrJ[c4 + 1];
            u.z = sA[r][2] * nrJ[c4 + 2];
            u.w = sA[r][3] * nrJ[c4 + 3];
            *(f4*)(out + idxA) = u;

            // lower tile: i = J+row > j = I+col
            size_t idxB = (size_t)(J + row) * n + (size_t)(I + c4);
            float nr_row = nrJ[row];   // nr[i] with i = J+row
            f4 w;
            w.x = sB[r][0] * nrI[c4 + 0] * (1.0f - Ash[c4 + 0][row] * nr_row);
            w.y = sB[r][1] * nrI[c4 + 1] * (1.0f - Ash[c4 + 1][row] * nr_row);
            w.z = sB[r][2] * nrI[c4 + 2] * (1.0f - Ash[c4 + 2][row] * nr_row);
            w.w = sB[r][3] * nrI[c4 + 3] * (1.0f - Ash[c4 + 3][row] * nr_row);
            *(f4*)(out + idxB) = w;
        }
    }
}

extern "C" void kernel_launch(void* const* d_in, const int* in_sizes, int n_in,
                              void* d_out, int out_size, void* d_ws, size_t ws_size,
                              hipStream_t stream) {
    const float*  rp = (const float*)d_in[0];   // root_probs (N)
    const float*  ep = (const float*)d_in[1];   // edge_probs (N,N)
    const float2* gr = (const float2*)d_in[2];  // g_root (N,2)
    const f4*     ge = (const f4*)d_in[3];      // g_edge (N,N,2) as f4
    float* out = (float*)d_out;
    const int n = in_sizes[0];

    const int nb = n / TS;                      // 2048/64 = 32
    const int pairs = nb * (nb + 1) / 2;        // 528 blocks
    dag_kernel<<<pairs, 256, 0, stream>>>(rp, gr, ep, ge, out, n);
}

// Round 6
// 15.004 us; speedup vs baseline: 1.1133x; 1.1133x over previous
//
#include <hip/hip_runtime.h>

// dag[i,j] = s[i,j]*nr[j] * (i<j ? 1 : (i>j ? 1 - s[j,i]*nr[i] : 0))
// s[i,j] = (ep[i,j]+ge[i,j,0]) > ((1-ep[i,j])+ge[i,j,1])
// nr[j]  = 1 - ((rp[j]+gr[j,0]) > ((1-rp[j])+gr[j,1]))

typedef float f4 __attribute__((ext_vector_type(4)));

constexpr int TS = 32;   // 32x32 tiles, 2080 blocks -> ~8 blocks/CU

__global__ __launch_bounds__(256) void dag_kernel(
    const float*  __restrict__ rp,
    const float2* __restrict__ gr2,
    const float*  __restrict__ ep,
    const f4*     __restrict__ ge4,
    float* __restrict__ out, int n)
{
    __shared__ float Ash[TS][TS + 1];  // raw sample s of tile A; +1 pad
    __shared__ float nrJ[TS];          // nr for cols J..J+31
    __shared__ float nrI[TS];          // nr for cols I..I+31

    // triangular pair decode: (bi,bj), bi <= bj
    int p = blockIdx.x;
    int a = (int)((sqrtf(8.0f * (float)p + 1.0f) - 1.0f) * 0.5f);
    while ((a + 1) * (a + 2) / 2 <= p) ++a;
    while (a * (a + 1) / 2 > p) --a;
    const int bi = p - a * (a + 1) / 2;
    const int bj = a;
    const int I = bi * TS, J = bj * TS;
    const bool diag = (bi == bj);

    const int t   = threadIdx.x;
    const int row = t >> 3;          // 0..31
    const int c4  = (t & 7) << 2;    // 0,4,...,28

    // ---- small nr loads first (feed the only barrier) ----
    float nr_val = 0.0f;
    if (t < 2 * TS) {
        int j = (t < TS) ? (J + t) : (I + (t - TS));
        float pj = rp[j]; float2 g = gr2[j];
        nr_val = ((pj + g.x) > ((1.0f - pj) + g.y)) ? 0.0f : 1.0f;
    }

    // ---- all 6 streaming loads issued before any compute ----
    const size_t idxA = (size_t)(I + row) * n + (size_t)(J + c4);
    const size_t idxB = (size_t)(J + row) * n + (size_t)(I + c4);
    const f4 epA = *(const f4*)(ep + idxA);
    const f4 qA0 = ge4[idxA >> 1];
    const f4 qA1 = ge4[(idxA >> 1) + 1];
    f4 epB, qB0, qB1;
    if (!diag) {
        epB = *(const f4*)(ep + idxB);
        qB0 = ge4[idxB >> 1];
        qB1 = ge4[(idxB >> 1) + 1];
    }

    if (t < TS)           nrJ[t] = nr_val;
    else if (t < 2 * TS)  nrI[t - TS] = nr_val;

    // ---- tile A raw samples -> LDS (nr applied after barrier) ----
    float sA[4];
    sA[0] = ((epA.x + qA0.x) > ((1.0f - epA.x) + qA0.y)) ? 1.0f : 0.0f;
    sA[1] = ((epA.y + qA0.z) > ((1.0f - epA.y) + qA0.w)) ? 1.0f : 0.0f;
    sA[2] = ((epA.z + qA1.x) > ((1.0f - epA.z) + qA1.y)) ? 1.0f : 0.0f;
    sA[3] = ((epA.w + qA1.z) > ((1.0f - epA.w) + qA1.w)) ? 1.0f : 0.0f;
    Ash[row][c4 + 0] = sA[0];
    Ash[row][c4 + 1] = sA[1];
    Ash[row][c4 + 2] = sA[2];
    Ash[row][c4 + 3] = sA[3];

    float sB[4];
    if (!diag) {
        sB[0] = ((epB.x + qB0.x) > ((1.0f - epB.x) + qB0.y)) ? 1.0f : 0.0f;
        sB[1] = ((epB.y + qB0.z) > ((1.0f - epB.y) + qB0.w)) ? 1.0f : 0.0f;
        sB[2] = ((epB.z + qB1.x) > ((1.0f - epB.z) + qB1.y)) ? 1.0f : 0.0f;
        sB[3] = ((epB.w + qB1.z) > ((1.0f - epB.w) + qB1.w)) ? 1.0f : 0.0f;
    }

    __syncthreads();   // single barrier: covers Ash, nrJ, nrI

    if (diag) {
        const float nr_row = nrJ[row];
        f4 v;
#pragma unroll
        for (int c = 0; c < 4; ++c) {
            int col = c4 + c;
            float x;
            if (row == col)      x = 0.0f;
            else if (row < col)  x = sA[c] * nrJ[col];
            else                 x = sA[c] * nrJ[col] * (1.0f - Ash[col][row] * nr_row);
            v[c] = x;
        }
        *(f4*)(out + idxA) = v;
    } else {
        // upper tile: i = I+row < j = J+col always
        f4 u;
        u.x = sA[0] * nrJ[c4 + 0];
        u.y = sA[1] * nrJ[c4 + 1];
        u.z = sA[2] * nrJ[c4 + 2];
        u.w = sA[3] * nrJ[c4 + 3];
        *(f4*)(out + idxA) = u;

        // lower tile: i = J+row > j = I+col
        const float nr_row = nrJ[row];   // nr[i], i = J+row
        f4 w;
        w.x = sB[0] * nrI[c4 + 0] * (1.0f - Ash[c4 + 0][row] * nr_row);
        w.y = sB[1] * nrI[c4 + 1] * (1.0f - Ash[c4 + 1][row] * nr_row);
        w.z = sB[2] * nrI[c4 + 2] * (1.0f - Ash[c4 + 2][row] * nr_row);
        w.w = sB[3] * nrI[c4 + 3] * (1.0f - Ash[c4 + 3][row] * nr_row);
        *(f4*)(out + idxB) = w;
    }
}

extern "C" void kernel_launch(void* const* d_in, const int* in_sizes, int n_in,
                              void* d_out, int out_size, void* d_ws, size_t ws_size,
                              hipStream_t stream) {
    const float*  rp = (const float*)d_in[0];   // root_probs (N)
    const float*  ep = (const float*)d_in[1];   // edge_probs (N,N)
    const float2* gr = (const float2*)d_in[2];  // g_root (N,2)
    const f4*     ge = (const f4*)d_in[3];      // g_edge (N,N,2) as f4
    float* out = (float*)d_out;
    const int n = in_sizes[0];

    const int nb = n / TS;                      // 2048/32 = 64
    const int pairs = nb * (nb + 1) / 2;        // 2080 blocks
    dag_kernel<<<pairs, 256, 0, stream>>>(rp, gr, ep, ge, out, n);
}

// Round 7
// 14.977 us; speedup vs baseline: 1.1153x; 1.0018x over previous
//
#include <hip/hip_runtime.h>

// dag[i,j] = s[i,j]*nr[j] * (i<j ? 1 : (i>j ? 1 - s[j,i]*nr[i] : 0))
// s[i,j] = (ep[i,j]+ge[i,j,0]) > ((1-ep[i,j])+ge[i,j,1])
// nr[j]  = 1 - ((rp[j]+gr[j,0]) > ((1-rp[j])+gr[j,1]))

typedef float f4 __attribute__((ext_vector_type(4)));

constexpr int TS = 32;   // 32x32 tiles, 2080 blocks

__global__ __launch_bounds__(256) void dag_kernel(
    const float*  __restrict__ rp,
    const float2* __restrict__ gr2,
    const float*  __restrict__ ep,
    const f4*     __restrict__ ge4,
    float* __restrict__ out, int n)
{
    __shared__ float Ash[TS][TS + 1];  // raw sample s of tile A; +1 pad
    __shared__ float nrJ[TS];          // nr for cols J..J+31
    __shared__ float nrI[TS];          // nr for cols I..I+31

    // triangular pair decode: (bi,bj), bi <= bj
    int p = blockIdx.x;
    int a = (int)((sqrtf(8.0f * (float)p + 1.0f) - 1.0f) * 0.5f);
    while ((a + 1) * (a + 2) / 2 <= p) ++a;
    while (a * (a + 1) / 2 > p) --a;
    const int bi = p - a * (a + 1) / 2;
    const int bj = a;
    const int I = bi * TS, J = bj * TS;
    const bool diag = (bi == bj);

    const int t   = threadIdx.x;
    const int row = t >> 3;          // 0..31
    const int c4  = (t & 7) << 2;    // 0,4,...,28

    // ---- small nr loads first (they feed the barrier) ----
    float nr_val = 0.0f;
    if (t < 2 * TS) {
        int j = (t < TS) ? (J + t) : (I + (t - TS));
        float pj = rp[j]; float2 g = gr2[j];
        nr_val = ((pj + g.x) > ((1.0f - pj) + g.y)) ? 0.0f : 1.0f;
    }

    // ---- streaming loads: A-tile (pre-barrier), then B-tile (post-barrier use) ----
    const size_t idxA = (size_t)(I + row) * n + (size_t)(J + c4);
    const size_t idxB = (size_t)(J + row) * n + (size_t)(I + c4);
    const f4 epA = *(const f4*)(ep + idxA);
    const f4 qA0 = ge4[idxA >> 1];
    const f4 qA1 = ge4[(idxA >> 1) + 1];
    f4 epB, qB0, qB1;
    if (!diag) {
        epB = *(const f4*)(ep + idxB);
        qB0 = ge4[idxB >> 1];
        qB1 = ge4[(idxB >> 1) + 1];
    }

    if (t < TS)           nrJ[t] = nr_val;
    else if (t < 2 * TS)  nrI[t - TS] = nr_val;

    // ---- tile A raw samples -> LDS ----
    float sA[4];
    sA[0] = ((epA.x + qA0.x) > ((1.0f - epA.x) + qA0.y)) ? 1.0f : 0.0f;
    sA[1] = ((epA.y + qA0.z) > ((1.0f - epA.y) + qA0.w)) ? 1.0f : 0.0f;
    sA[2] = ((epA.z + qA1.x) > ((1.0f - epA.z) + qA1.y)) ? 1.0f : 0.0f;
    sA[3] = ((epA.w + qA1.z) > ((1.0f - epA.w) + qA1.w)) ? 1.0f : 0.0f;
    Ash[row][c4 + 0] = sA[0];
    Ash[row][c4 + 1] = sA[1];
    Ash[row][c4 + 2] = sA[2];
    Ash[row][c4 + 3] = sA[3];

    // ---- barrier that waits ONLY on LDS (B-tile global loads stay in flight) ----
    asm volatile("s_waitcnt lgkmcnt(0)" ::: "memory");
    __builtin_amdgcn_s_barrier();
    __builtin_amdgcn_sched_barrier(0);   // keep post-barrier LDS reads below the barrier

    if (diag) {
        const float nr_row = nrJ[row];
        f4 v;
#pragma unroll
        for (int c = 0; c < 4; ++c) {
            int col = c4 + c;
            float x;
            if (row == col)      x = 0.0f;
            else if (row < col)  x = sA[c] * nrJ[col];
            else                 x = sA[c] * nrJ[col] * (1.0f - Ash[col][row] * nr_row);
            v[c] = x;
        }
        *(f4*)(out + idxA) = v;
    } else {
        // upper tile: i = I+row < j = J+col always (B loads still landing here)
        f4 u;
        u.x = sA[0] * nrJ[c4 + 0];
        u.y = sA[1] * nrJ[c4 + 1];
        u.z = sA[2] * nrJ[c4 + 2];
        u.w = sA[3] * nrJ[c4 + 3];
        *(f4*)(out + idxA) = u;

        // tile B samples (compiler waits on B loads exactly here)
        float sB[4];
        sB[0] = ((epB.x + qB0.x) > ((1.0f - epB.x) + qB0.y)) ? 1.0f : 0.0f;
        sB[1] = ((epB.y + qB0.z) > ((1.0f - epB.y) + qB0.w)) ? 1.0f : 0.0f;
        sB[2] = ((epB.z + qB1.x) > ((1.0f - epB.z) + qB1.y)) ? 1.0f : 0.0f;
        sB[3] = ((epB.w + qB1.z) > ((1.0f - epB.w) + qB1.w)) ? 1.0f : 0.0f;

        // lower tile: i = J+row > j = I+col
        const float nr_row = nrJ[row];   // nr[i], i = J+row
        f4 w;
        w.x = sB[0] * nrI[c4 + 0] * (1.0f - Ash[c4 + 0][row] * nr_row);
        w.y = sB[1] * nrI[c4 + 1] * (1.0f - Ash[c4 + 1][row] * nr_row);
        w.z = sB[2] * nrI[c4 + 2] * (1.0f - Ash[c4 + 2][row] * nr_row);
        w.w = sB[3] * nrI[c4 + 3] * (1.0f - Ash[c4 + 3][row] * nr_row);
        *(f4*)(out + idxB) = w;
    }
}

extern "C" void kernel_launch(void* const* d_in, const int* in_sizes, int n_in,
                              void* d_out, int out_size, void* d_ws, size_t ws_size,
                              hipStream_t stream) {
    const float*  rp = (const float*)d_in[0];   // root_probs (N)
    const float*  ep = (const float*)d_in[1];   // edge_probs (N,N)
    const float2* gr = (const float2*)d_in[2];  // g_root (N,2)
    const f4*     ge = (const f4*)d_in[3];      // g_edge (N,N,2) as f4
    float* out = (float*)d_out;
    const int n = in_sizes[0];

    const int nb = n / TS;                      // 2048/32 = 64
    const int pairs = nb * (nb + 1) / 2;        // 2080 blocks
    dag_kernel<<<pairs, 256, 0, stream>>>(rp, gr, ep, ge, out, n);
}